// Round 13
// baseline (225.457 us; speedup 1.0000x reference)
//
// GCNEncoder MI355X kernel — v9: channel-split 2-pass gathers (halved random
// working set per pass -> ~2x L2 hit rate); memset folded into k_pre.
// Resubmission r12: identical to r11 source; r11 died to UnresponsiveContainer
// before compile (dead pod lease), never executed.
#include <hip/hip_runtime.h>

#define NN 100000
#define NE 1600000
#define NB 391            // ceil(NN/256) buckets of 256 nodes (bucket = dst >> 8)
#define CHUNK 4096
#define NCHUNK 391        // ceil(NE/CHUNK)

typedef __attribute__((ext_vector_type(8))) short short8_t;
typedef __attribute__((ext_vector_type(4))) float float4_t;

// ---- bf16 helpers (RNE pack, bit-op unpack) ----
__device__ inline unsigned short f2bf(float f) {
    unsigned int u = __float_as_uint(f);
    unsigned int r = u + 0x7fffu + ((u >> 16) & 1u);
    return (unsigned short)(r >> 16);
}
__device__ inline float bf_lo(unsigned int u) { return __uint_as_float(u << 16); }
__device__ inline float bf_hi(unsigned int u) { return __uint_as_float(u & 0xffff0000u); }

// ---------------- prologue: W1 transpose + zero bhist ----------------
__global__ __launch_bounds__(256) void k_pre(const float* __restrict__ W1,
                                             unsigned short* __restrict__ wtb,
                                             int* __restrict__ bhist) {
    int f = blockIdx.x * 256 + threadIdx.x;      // 0..8191
    int c = f >> 7, k = f & 127;
    wtb[f] = f2bf(W1[k * 64 + c]);
    if (f < NB) bhist[f] = 0;
}

// ---------------- Pass A: coarse histogram (LDS-privatized) ----------------
__global__ __launch_bounds__(256) void k_hist(const int* __restrict__ dst,
                                              int* __restrict__ bhist) {
    __shared__ int lh[NB];
    int t = threadIdx.x;
    for (int i = t; i < NB; i += 256) lh[i] = 0;
    __syncthreads();
    for (int e = blockIdx.x * 256 + t; e < NE; e += 256 * 256)
        atomicAdd(&lh[dst[e] >> 8], 1);
    __syncthreads();
    for (int i = t; i < NB; i += 256)
        if (lh[i]) atomicAdd(&bhist[i], lh[i]);
}

// ---------------- Pass B: scan buckets -> boff, bcursor ----------------
__global__ __launch_bounds__(256) void k_scanb(const int* __restrict__ bhist,
                                               int* __restrict__ boff,
                                               int* __restrict__ bcur) {
    __shared__ int sh[256];
    int t = threadIdx.x;
    int base = t * 2;
    int v0 = (base + 0 < NB) ? bhist[base + 0] : 0;
    int v1 = (base + 1 < NB) ? bhist[base + 1] : 0;
    int tsum = v0 + v1;
    sh[t] = tsum;
    __syncthreads();
    for (int d = 1; d < 256; d <<= 1) {
        int x = (t >= d) ? sh[t - d] : 0;
        __syncthreads();
        sh[t] += x;
        __syncthreads();
    }
    int excl = sh[t] - tsum;
    if (base + 0 < NB) { boff[base + 0] = excl;      bcur[base + 0] = excl; }
    if (base + 1 < NB) { boff[base + 1] = excl + v0; bcur[base + 1] = excl + v0; }
    if (t == 255) boff[NB] = sh[255];   // == NE
}

// ---------------- FUSED: GEMM1 (MFMA, unscaled) ∥ bscatter ----------------
__global__ __launch_bounds__(512) void k_fuse(const float* __restrict__ x,
                                              const unsigned short* __restrict__ wtb,
                                              unsigned short* __restrict__ t1b,
                                              const int* __restrict__ src,
                                              const int* __restrict__ dst,
                                              int* __restrict__ bcur,
                                              unsigned int* __restrict__ pairs) {
    __shared__ __align__(16) unsigned char smem[52224];
    const int b = blockIdx.x;
    const int t = threadIdx.x;

    if ((b % 3) == 2) {
        // ---- bscatter role ----
        int* lh    = (int*)smem;          // [NB]
        int* lbase = lh + NB;             // [NB]
        int e0 = (b / 3) * CHUNK;
        int e1 = min(e0 + CHUNK, NE);
        for (int i = t; i < NB; i += 512) lh[i] = 0;
        __syncthreads();
        for (int e = e0 + t; e < e1; e += 512)
            atomicAdd(&lh[dst[e] >> 8], 1);
        __syncthreads();
        int rot = (int)(((unsigned)(b / 3) * 97u) % NB);   // stagger atomic bursts
        for (int i = t; i < NB; i += 512) {
            int ii = i + rot; if (ii >= NB) ii -= NB;
            int h = lh[ii];
            lbase[ii] = h ? atomicAdd(&bcur[ii], h) : 0;
        }
        __syncthreads();
        for (int i = t; i < NB; i += 512) lh[i] = 0;   // reuse as cursor
        __syncthreads();
        for (int e = e0 + t; e < e1; e += 512) {
            int d = dst[e];
            int bk = d >> 8;
            int r = atomicAdd(&lh[bk], 1);
            pairs[lbase[bk] + r] = (unsigned int)src[e] | ((unsigned int)(d & 255) << 17);
        }
    } else {
        // ---- gemm1 role ----
        unsigned short* lx = (unsigned short*)smem;            // [128*136]
        unsigned short* lw = (unsigned short*)(smem + 34816);  // [64*136]
        const int tile = 2 * (b / 3) + (b % 3);
        const int row0 = tile * 128;
        const int nrows = min(128, NN - row0);

        #pragma unroll
        for (int i = 0; i < 8; ++i) {
            int f = t + i * 512;            // 0..4095
            int r = f >> 5, c4 = f & 31;
            float4 v = make_float4(0.f, 0.f, 0.f, 0.f);
            if (r < nrows) v = ((const float4*)(x + (size_t)(row0 + r) * 128))[c4];
            ushort4 o;
            o.x = f2bf(v.x); o.y = f2bf(v.y); o.z = f2bf(v.z); o.w = f2bf(v.w);
            *(ushort4*)&lx[r * 136 + c4 * 4] = o;
        }
        #pragma unroll
        for (int i = 0; i < 2; ++i) {
            int f = t + i * 512;            // 0..1023 ; f = c*16 + c8
            int c = f >> 4, c8 = f & 15;
            uint4 v = ((const uint4*)wtb)[f];
            *(uint4*)&lw[c * 136 + c8 * 8] = v;
        }
        __syncthreads();

        const int w = t >> 6, l = t & 63;
        const int m15 = l & 15, kg = l >> 4;
        const unsigned short* pa = &lx[(w * 16 + m15) * 136 + kg * 8];
        const unsigned short* pb = &lw[m15 * 136 + kg * 8];

        float4_t acc[4];
        #pragma unroll
        for (int cb = 0; cb < 4; ++cb) acc[cb] = (float4_t){0.f, 0.f, 0.f, 0.f};

        #pragma unroll
        for (int ks = 0; ks < 4; ++ks) {
            short8_t a = *(const short8_t*)(pa + ks * 32);
            #pragma unroll
            for (int cb = 0; cb < 4; ++cb) {
                short8_t bb = *(const short8_t*)(pb + cb * (16 * 136) + ks * 32);
                acc[cb] = __builtin_amdgcn_mfma_f32_16x16x32_bf16(a, bb, acc[cb], 0, 0, 0);
            }
        }

        #pragma unroll
        for (int r = 0; r < 4; ++r) {
            int lrow = w * 16 + kg * 4 + r;
            if (lrow < nrows) {
                size_t grow = (size_t)(row0 + lrow);
                #pragma unroll
                for (int cb = 0; cb < 4; ++cb)
                    t1b[grow * 64 + cb * 16 + m15] = f2bf(acc[cb][r]);
            }
        }
    }
}

// ---------------- Pass D: per-bucket fine sort + dinv + csr_off ----------------
__global__ __launch_bounds__(256) void k_fine(const unsigned int* __restrict__ pairs,
                                              const int* __restrict__ boff,
                                              int* __restrict__ csr_off,
                                              int* __restrict__ csr_src,
                                              float* __restrict__ dinv) {
    __shared__ int lcnt[256];
    __shared__ int sc[256];
    __shared__ int lofs[256];
    int t = threadIdx.x;
    int b = blockIdx.x;
    int n0 = b << 8;
    int nnode = min(256, NN - n0);
    int bO = boff[b], bE = boff[b + 1];

    lcnt[t] = 0;
    __syncthreads();
    for (int e = bO + t; e < bE; e += 256)
        atomicAdd(&lcnt[pairs[e] >> 17], 1);
    __syncthreads();
    sc[t] = lcnt[t];
    __syncthreads();
    for (int d = 1; d < 256; d <<= 1) {
        int x = (t >= d) ? sc[t - d] : 0;
        __syncthreads();
        sc[t] += x;
        __syncthreads();
    }
    {
        int excl = sc[t] - lcnt[t];
        lofs[t] = excl;
        if (t < nnode) {
            int n = n0 + t;
            csr_off[n] = bO + excl;
            dinv[n] = rsqrtf(1.0f + (float)lcnt[t]);
        }
        lcnt[t] = 0;   // reuse as cursor
    }
    if (b == NB - 1 && t == 0) csr_off[NN] = NE;
    __syncthreads();
    for (int e = bO + t; e < bE; e += 256) {
        unsigned int w = pairs[e];
        int li = (int)(w >> 17);
        int r = atomicAdd(&lcnt[li], 1);
        csr_src[bO + lofs[li] + r] = (int)(w & 0x1FFFFu);
    }
}

// ---------------- gather1 (2-pass channel-split, 4 lanes/node) ----------------
// acc = dn*t1[n] + sum_e dinv[s]*t1[s];  out = bf16( dn*relu(dn*acc + b1) )
__global__ __launch_bounds__(256) void k_gather4(const int* __restrict__ off,
                                                 const int* __restrict__ csr,
                                                 const float* __restrict__ dinv,
                                                 const unsigned short* __restrict__ hb,
                                                 const float* __restrict__ bias,
                                                 unsigned int* __restrict__ outp) {
    int idx = blockIdx.x * 256 + threadIdx.x;   // 4 lanes per node
    int n = idx >> 2;
    if (n >= NN) return;
    int c4 = idx & 3;
    const uint4* h4 = (const uint4*)hb;         // row stride = 8 uint4 (64 bf16)
    float dn = dinv[n];
    int b = off[n], e = off[n + 1];
    #pragma unroll
    for (int p = 0; p < 2; ++p) {               // channel half p: cols [p*32, p*32+32)
        int col = p * 4 + c4;                   // uint4 index in row
        float acc[8];
        {
            uint4 v = h4[(size_t)n * 8 + col];  // self term: dn * t1[n]
            acc[0] = dn * bf_lo(v.x); acc[1] = dn * bf_hi(v.x);
            acc[2] = dn * bf_lo(v.y); acc[3] = dn * bf_hi(v.y);
            acc[4] = dn * bf_lo(v.z); acc[5] = dn * bf_hi(v.z);
            acc[6] = dn * bf_lo(v.w); acc[7] = dn * bf_hi(v.w);
        }
        for (int i = b; i < e; ++i) {
            int s = csr[i];
            float w = dinv[s];
            uint4 v = h4[(size_t)s * 8 + col];
            acc[0] += w * bf_lo(v.x); acc[1] += w * bf_hi(v.x);
            acc[2] += w * bf_lo(v.y); acc[3] += w * bf_hi(v.y);
            acc[4] += w * bf_lo(v.z); acc[5] += w * bf_hi(v.z);
            acc[6] += w * bf_lo(v.w); acc[7] += w * bf_hi(v.w);
        }
        float4 b0 = ((const float4*)bias)[col * 2];
        float4 b1v = ((const float4*)bias)[col * 2 + 1];
        float o[8];
        o[0] = dn * fmaxf(dn * acc[0] + b0.x, 0.f);
        o[1] = dn * fmaxf(dn * acc[1] + b0.y, 0.f);
        o[2] = dn * fmaxf(dn * acc[2] + b0.z, 0.f);
        o[3] = dn * fmaxf(dn * acc[3] + b0.w, 0.f);
        o[4] = dn * fmaxf(dn * acc[4] + b1v.x, 0.f);
        o[5] = dn * fmaxf(dn * acc[5] + b1v.y, 0.f);
        o[6] = dn * fmaxf(dn * acc[6] + b1v.z, 0.f);
        o[7] = dn * fmaxf(dn * acc[7] + b1v.w, 0.f);
        uint4 pk;
        pk.x = (unsigned int)f2bf(o[0]) | ((unsigned int)f2bf(o[1]) << 16);
        pk.y = (unsigned int)f2bf(o[2]) | ((unsigned int)f2bf(o[3]) << 16);
        pk.z = (unsigned int)f2bf(o[4]) | ((unsigned int)f2bf(o[5]) << 16);
        pk.w = (unsigned int)f2bf(o[6]) | ((unsigned int)f2bf(o[7]) << 16);
        ((uint4*)outp)[(size_t)n * 8 + col] = pk;
    }
}

// ---------------- Fused gather2 + GEMM2 (2-pass channel-split phase A) ----------------
__global__ __launch_bounds__(256) void k_gg2(const int* __restrict__ off,
                                             const int* __restrict__ csr,
                                             const float* __restrict__ dinv,
                                             const unsigned short* __restrict__ hb,
                                             const float* __restrict__ W2, const float* __restrict__ b2,
                                             const float* __restrict__ W3, const float* __restrict__ b3,
                                             float* __restrict__ out) {
    __shared__ float as_[64][72];     // +8 pad
    __shared__ float wc[64 * 64];
    __shared__ float bc[64];
    const int t = threadIdx.x;
    const int row0 = blockIdx.x * 64;
    const int nrows = min(64, NN - row0);

    #pragma unroll
    for (int i = 0; i < 16; ++i) {
        int f = t + i * 256;
        int k = f >> 6, c = f & 63;
        wc[f] = (c < 32) ? W2[k * 32 + c] : W3[k * 32 + (c - 32)];
    }
    if (t < 64) bc[t] = (t < 32) ? b2[t] : b3[t - 32];

    // phase A: gather agg2 rows into LDS (fp32), 2 channel-half passes
    {
        const int nl = t >> 2;              // 0..63
        const int n = row0 + nl;
        const int c4 = t & 3;
        const uint4* h4 = (const uint4*)hb;
        float dn = (n < NN) ? dinv[n] : 0.f;
        int b = 0, e = 0;
        if (n < NN) { b = off[n]; e = off[n + 1]; }
        #pragma unroll
        for (int p = 0; p < 2; ++p) {
            int col = p * 4 + c4;
            float acc[8];
            if (n < NN) {
                uint4 v = h4[(size_t)n * 8 + col];      // self (h1b prescaled)
                acc[0] = bf_lo(v.x); acc[1] = bf_hi(v.x);
                acc[2] = bf_lo(v.y); acc[3] = bf_hi(v.y);
                acc[4] = bf_lo(v.z); acc[5] = bf_hi(v.z);
                acc[6] = bf_lo(v.w); acc[7] = bf_hi(v.w);
                for (int i = b; i < e; ++i) {
                    int s = csr[i];
                    uint4 u = h4[(size_t)s * 8 + col];
                    acc[0] += bf_lo(u.x); acc[1] += bf_hi(u.x);
                    acc[2] += bf_lo(u.y); acc[3] += bf_hi(u.y);
                    acc[4] += bf_lo(u.z); acc[5] += bf_hi(u.z);
                    acc[6] += bf_lo(u.w); acc[7] += bf_hi(u.w);
                }
                #pragma unroll
                for (int j = 0; j < 8; ++j) acc[j] *= dn;
            } else {
                #pragma unroll
                for (int j = 0; j < 8; ++j) acc[j] = 0.f;
            }
            float* dp = &as_[nl][col * 8];
            #pragma unroll
            for (int j = 0; j < 8; ++j) dp[j] = acc[j];
        }
    }
    __syncthreads();

    // phase B: GEMM
    const int tc = t & 15;
    const int tr = t >> 4;
    float acc[4][4];
    #pragma unroll
    for (int i = 0; i < 4; ++i)
        #pragma unroll
        for (int j = 0; j < 4; ++j) acc[i][j] = 0.f;

    #pragma unroll 4
    for (int k = 0; k < 64; ++k) {
        float4 wv = *(const float4*)&wc[k * 64 + tc * 4];
        #pragma unroll
        for (int i = 0; i < 4; ++i) {
            float xv = as_[tr * 4 + i][k];
            acc[i][0] += xv * wv.x; acc[i][1] += xv * wv.y;
            acc[i][2] += xv * wv.z; acc[i][3] += xv * wv.w;
        }
    }
    const int c0 = tc * 4;
    float4 bias = *(float4*)&bc[c0];
    #pragma unroll
    for (int i = 0; i < 4; ++i) {
        int r = tr * 4 + i;
        if (r < nrows) {
            float4 o = make_float4(acc[i][0] + bias.x, acc[i][1] + bias.y,
                                   acc[i][2] + bias.z, acc[i][3] + bias.w);
            size_t row = (size_t)(row0 + r);
            float* p = (tc < 8) ? (out + row * 32 + c0)
                                : (out + (size_t)NN * 32 + row * 32 + (c0 - 32));
            *(float4*)p = o;
        }
    }
}

extern "C" void kernel_launch(void* const* d_in, const int* in_sizes, int n_in,
                              void* d_out, int out_size, void* d_ws, size_t ws_size,
                              hipStream_t stream) {
    const float* x  = (const float*)d_in[0];
    const int* edges = (const int*)d_in[1];
    const float* W1 = (const float*)d_in[2];
    const float* b1 = (const float*)d_in[3];
    const float* W2 = (const float*)d_in[4];
    const float* b2 = (const float*)d_in[5];
    const float* W3 = (const float*)d_in[6];
    const float* b3 = (const float*)d_in[7];
    float* out = (float*)d_out;

    const int* srcs = edges;            // edges[0]
    const int* dsts = edges + NE;       // edges[1]

    // ws layout (4-byte words), total 8,205,280 words = 32.8 MB
    int*   csr_off = (int*)d_ws;                    // [NN+1]
    float* dinv    = (float*)((int*)d_ws + 100004); // [NN]
    int*   csr_src = (int*)d_ws + 200004;           // [NE]
    int*   bhist   = (int*)d_ws + 1800004;          // [NB]
    int*   boff    = (int*)d_ws + 1800396;          // [NB+1]
    int*   bcur    = (int*)d_ws + 1800788;          // [NB]
    unsigned short* wtb = (unsigned short*)((int*)d_ws + 1801184); // [64*128] bf16
    // region A: t1b [NN*64] bf16 — exclusive (written concurrently with pairs!)
    unsigned short* t1b = (unsigned short*)((int*)d_ws + 1805280); // 3.2e6 words
    // region B: pairs [NE uint] then h1b [NN*64] bf16 (pairs dead after k_fine)
    unsigned int*   pairs = (unsigned int*)((int*)d_ws + 5005280);
    unsigned short* h1b   = (unsigned short*)pairs;

    dim3 blk(256);
    const int gN4 = (NN * 4 + 255) / 256;   // 1563
    const int gT  = (NN + 63) / 64;         // 1563

    // prologue: W1 transpose + zero bhist; histogram; bucket scan
    k_pre<<<32, blk, 0, stream>>>(W1, wtb, bhist);
    k_hist<<<256, blk, 0, stream>>>(dsts, bhist);
    k_scanb<<<1, blk, 0, stream>>>(bhist, boff, bcur);

    // fused: GEMM1 (782 tiles) ∥ bscatter (391 chunks), interleaved 2:1
    k_fuse<<<3 * NCHUNK, dim3(512), 0, stream>>>(x, wtb, t1b, srcs, dsts, bcur, pairs);

    k_fine<<<NB, blk, 0, stream>>>(pairs, boff, csr_off, csr_src, dinv);

    // conv1 aggregation: h1b = bf16(dinv*relu(dinv*Agg(t1)+b1)), 2-pass
    k_gather4<<<gN4, blk, 0, stream>>>(csr_off, csr_src, dinv, t1b, b1,
                                       (unsigned int*)h1b);
    // conv2/3: fused Agg(h1) + both GEMMs, 2-pass gather phase
    k_gg2<<<gT, blk, 0, stream>>>(csr_off, csr_src, dinv, h1b, W2, b2, W3, b3, out);
}

// Round 14
// 163.218 us; speedup vs baseline: 1.3813x; 1.3813x over previous
//
// GCNEncoder MI355X kernel — v10: v8 base (152 µs) + gg2 phase A reworked to
// 8 lanes/node / 32-row tiles (1 load per edge per lane, 26 KB LDS).
// v9's 2-pass channel split REVERTED (2x regression: latency-bound, not L2-bound).
#include <hip/hip_runtime.h>

#define NN 100000
#define NE 1600000
#define NB 391            // ceil(NN/256) buckets of 256 nodes (bucket = dst >> 8)
#define CHUNK 4096
#define NCHUNK 391        // ceil(NE/CHUNK)

typedef __attribute__((ext_vector_type(8))) short short8_t;
typedef __attribute__((ext_vector_type(4))) float float4_t;

// ---- bf16 helpers (RNE pack, bit-op unpack) ----
__device__ inline unsigned short f2bf(float f) {
    unsigned int u = __float_as_uint(f);
    unsigned int r = u + 0x7fffu + ((u >> 16) & 1u);
    return (unsigned short)(r >> 16);
}
__device__ inline float bf_lo(unsigned int u) { return __uint_as_float(u << 16); }
__device__ inline float bf_hi(unsigned int u) { return __uint_as_float(u & 0xffff0000u); }

// ---------------- prologue: W1 transpose + zero bhist ----------------
__global__ __launch_bounds__(256) void k_pre(const float* __restrict__ W1,
                                             unsigned short* __restrict__ wtb,
                                             int* __restrict__ bhist) {
    int f = blockIdx.x * 256 + threadIdx.x;      // 0..8191
    int c = f >> 7, k = f & 127;
    wtb[f] = f2bf(W1[k * 64 + c]);
    if (f < NB) bhist[f] = 0;
}

// ---------------- Pass A: coarse histogram (LDS-privatized) ----------------
__global__ __launch_bounds__(256) void k_hist(const int* __restrict__ dst,
                                              int* __restrict__ bhist) {
    __shared__ int lh[NB];
    int t = threadIdx.x;
    for (int i = t; i < NB; i += 256) lh[i] = 0;
    __syncthreads();
    for (int e = blockIdx.x * 256 + t; e < NE; e += 256 * 256)
        atomicAdd(&lh[dst[e] >> 8], 1);
    __syncthreads();
    for (int i = t; i < NB; i += 256)
        if (lh[i]) atomicAdd(&bhist[i], lh[i]);
}

// ---------------- Pass B: scan buckets -> boff, bcursor ----------------
__global__ __launch_bounds__(256) void k_scanb(const int* __restrict__ bhist,
                                               int* __restrict__ boff,
                                               int* __restrict__ bcur) {
    __shared__ int sh[256];
    int t = threadIdx.x;
    int base = t * 2;
    int v0 = (base + 0 < NB) ? bhist[base + 0] : 0;
    int v1 = (base + 1 < NB) ? bhist[base + 1] : 0;
    int tsum = v0 + v1;
    sh[t] = tsum;
    __syncthreads();
    for (int d = 1; d < 256; d <<= 1) {
        int x = (t >= d) ? sh[t - d] : 0;
        __syncthreads();
        sh[t] += x;
        __syncthreads();
    }
    int excl = sh[t] - tsum;
    if (base + 0 < NB) { boff[base + 0] = excl;      bcur[base + 0] = excl; }
    if (base + 1 < NB) { boff[base + 1] = excl + v0; bcur[base + 1] = excl + v0; }
    if (t == 255) boff[NB] = sh[255];   // == NE
}

// ---------------- FUSED: GEMM1 (MFMA, unscaled) ∥ bscatter ----------------
__global__ __launch_bounds__(512) void k_fuse(const float* __restrict__ x,
                                              const unsigned short* __restrict__ wtb,
                                              unsigned short* __restrict__ t1b,
                                              const int* __restrict__ src,
                                              const int* __restrict__ dst,
                                              int* __restrict__ bcur,
                                              unsigned int* __restrict__ pairs) {
    __shared__ __align__(16) unsigned char smem[52224];
    const int b = blockIdx.x;
    const int t = threadIdx.x;

    if ((b % 3) == 2) {
        // ---- bscatter role ----
        int* lh    = (int*)smem;          // [NB]
        int* lbase = lh + NB;             // [NB]
        int e0 = (b / 3) * CHUNK;
        int e1 = min(e0 + CHUNK, NE);
        for (int i = t; i < NB; i += 512) lh[i] = 0;
        __syncthreads();
        for (int e = e0 + t; e < e1; e += 512)
            atomicAdd(&lh[dst[e] >> 8], 1);
        __syncthreads();
        int rot = (int)(((unsigned)(b / 3) * 97u) % NB);   // stagger atomic bursts
        for (int i = t; i < NB; i += 512) {
            int ii = i + rot; if (ii >= NB) ii -= NB;
            int h = lh[ii];
            lbase[ii] = h ? atomicAdd(&bcur[ii], h) : 0;
        }
        __syncthreads();
        for (int i = t; i < NB; i += 512) lh[i] = 0;   // reuse as cursor
        __syncthreads();
        for (int e = e0 + t; e < e1; e += 512) {
            int d = dst[e];
            int bk = d >> 8;
            int r = atomicAdd(&lh[bk], 1);
            pairs[lbase[bk] + r] = (unsigned int)src[e] | ((unsigned int)(d & 255) << 17);
        }
    } else {
        // ---- gemm1 role ----
        unsigned short* lx = (unsigned short*)smem;            // [128*136]
        unsigned short* lw = (unsigned short*)(smem + 34816);  // [64*136]
        const int tile = 2 * (b / 3) + (b % 3);
        const int row0 = tile * 128;
        const int nrows = min(128, NN - row0);

        #pragma unroll
        for (int i = 0; i < 8; ++i) {
            int f = t + i * 512;            // 0..4095
            int r = f >> 5, c4 = f & 31;
            float4 v = make_float4(0.f, 0.f, 0.f, 0.f);
            if (r < nrows) v = ((const float4*)(x + (size_t)(row0 + r) * 128))[c4];
            ushort4 o;
            o.x = f2bf(v.x); o.y = f2bf(v.y); o.z = f2bf(v.z); o.w = f2bf(v.w);
            *(ushort4*)&lx[r * 136 + c4 * 4] = o;
        }
        #pragma unroll
        for (int i = 0; i < 2; ++i) {
            int f = t + i * 512;            // 0..1023 ; f = c*16 + c8
            int c = f >> 4, c8 = f & 15;
            uint4 v = ((const uint4*)wtb)[f];
            *(uint4*)&lw[c * 136 + c8 * 8] = v;
        }
        __syncthreads();

        const int w = t >> 6, l = t & 63;
        const int m15 = l & 15, kg = l >> 4;
        const unsigned short* pa = &lx[(w * 16 + m15) * 136 + kg * 8];
        const unsigned short* pb = &lw[m15 * 136 + kg * 8];

        float4_t acc[4];
        #pragma unroll
        for (int cb = 0; cb < 4; ++cb) acc[cb] = (float4_t){0.f, 0.f, 0.f, 0.f};

        #pragma unroll
        for (int ks = 0; ks < 4; ++ks) {
            short8_t a = *(const short8_t*)(pa + ks * 32);
            #pragma unroll
            for (int cb = 0; cb < 4; ++cb) {
                short8_t bb = *(const short8_t*)(pb + cb * (16 * 136) + ks * 32);
                acc[cb] = __builtin_amdgcn_mfma_f32_16x16x32_bf16(a, bb, acc[cb], 0, 0, 0);
            }
        }

        #pragma unroll
        for (int r = 0; r < 4; ++r) {
            int lrow = w * 16 + kg * 4 + r;
            if (lrow < nrows) {
                size_t grow = (size_t)(row0 + lrow);
                #pragma unroll
                for (int cb = 0; cb < 4; ++cb)
                    t1b[grow * 64 + cb * 16 + m15] = f2bf(acc[cb][r]);
            }
        }
    }
}

// ---------------- Pass D: per-bucket fine sort + dinv + csr_off ----------------
__global__ __launch_bounds__(256) void k_fine(const unsigned int* __restrict__ pairs,
                                              const int* __restrict__ boff,
                                              int* __restrict__ csr_off,
                                              int* __restrict__ csr_src,
                                              float* __restrict__ dinv) {
    __shared__ int lcnt[256];
    __shared__ int sc[256];
    __shared__ int lofs[256];
    int t = threadIdx.x;
    int b = blockIdx.x;
    int n0 = b << 8;
    int nnode = min(256, NN - n0);
    int bO = boff[b], bE = boff[b + 1];

    lcnt[t] = 0;
    __syncthreads();
    for (int e = bO + t; e < bE; e += 256)
        atomicAdd(&lcnt[pairs[e] >> 17], 1);
    __syncthreads();
    sc[t] = lcnt[t];
    __syncthreads();
    for (int d = 1; d < 256; d <<= 1) {
        int x = (t >= d) ? sc[t - d] : 0;
        __syncthreads();
        sc[t] += x;
        __syncthreads();
    }
    {
        int excl = sc[t] - lcnt[t];
        lofs[t] = excl;
        if (t < nnode) {
            int n = n0 + t;
            csr_off[n] = bO + excl;
            dinv[n] = rsqrtf(1.0f + (float)lcnt[t]);
        }
        lcnt[t] = 0;   // reuse as cursor
    }
    if (b == NB - 1 && t == 0) csr_off[NN] = NE;
    __syncthreads();
    for (int e = bO + t; e < bE; e += 256) {
        unsigned int w = pairs[e];
        int li = (int)(w >> 17);
        int r = atomicAdd(&lcnt[li], 1);
        csr_src[bO + lofs[li] + r] = (int)(w & 0x1FFFFu);
    }
}

// ---------------- gather1: h1b = bf16( dinv[n]*relu( dinv[n]*acc + b1 ) ) ----------------
// acc = dinv[n]*t1[n] + sum_e dinv[s]*t1[s]   (t1b unscaled; 8 lanes/node, 8 ch/lane)
__global__ __launch_bounds__(256) void k_gather8(const int* __restrict__ off,
                                                 const int* __restrict__ csr,
                                                 const float* __restrict__ dinv,
                                                 const unsigned short* __restrict__ hb,
                                                 const float* __restrict__ bias,
                                                 unsigned int* __restrict__ outp) {
    int idx = blockIdx.x * 256 + threadIdx.x;   // 8 lanes per node
    int n = idx >> 3;
    if (n >= NN) return;
    int c8 = idx & 7;                           // channels c8*8 .. c8*8+7
    const uint4* h4 = (const uint4*)hb;         // row stride = 8 uint4 (64 bf16)
    float dn = dinv[n];
    float a0[8], a1[8];
    {
        uint4 v = h4[(size_t)n * 8 + c8];       // self term: dn * t1[n]
        a0[0] = dn * bf_lo(v.x); a0[1] = dn * bf_hi(v.x);
        a0[2] = dn * bf_lo(v.y); a0[3] = dn * bf_hi(v.y);
        a0[4] = dn * bf_lo(v.z); a0[5] = dn * bf_hi(v.z);
        a0[6] = dn * bf_lo(v.w); a0[7] = dn * bf_hi(v.w);
        #pragma unroll
        for (int j = 0; j < 8; ++j) a1[j] = 0.f;
    }
    int b = off[n], e = off[n + 1];
    int i = b;
    for (; i + 1 < e; i += 2) {                 // 2-edge unroll, dual accumulators
        int s0 = csr[i], s1 = csr[i + 1];
        float w0 = dinv[s0], w1 = dinv[s1];
        uint4 v0 = h4[(size_t)s0 * 8 + c8];
        uint4 v1 = h4[(size_t)s1 * 8 + c8];
        a0[0] += w0 * bf_lo(v0.x); a0[1] += w0 * bf_hi(v0.x);
        a0[2] += w0 * bf_lo(v0.y); a0[3] += w0 * bf_hi(v0.y);
        a0[4] += w0 * bf_lo(v0.z); a0[5] += w0 * bf_hi(v0.z);
        a0[6] += w0 * bf_lo(v0.w); a0[7] += w0 * bf_hi(v0.w);
        a1[0] += w1 * bf_lo(v1.x); a1[1] += w1 * bf_hi(v1.x);
        a1[2] += w1 * bf_lo(v1.y); a1[3] += w1 * bf_hi(v1.y);
        a1[4] += w1 * bf_lo(v1.z); a1[5] += w1 * bf_hi(v1.z);
        a1[6] += w1 * bf_lo(v1.w); a1[7] += w1 * bf_hi(v1.w);
    }
    if (i < e) {
        int s = csr[i];
        float w = dinv[s];
        uint4 v = h4[(size_t)s * 8 + c8];
        a0[0] += w * bf_lo(v.x); a0[1] += w * bf_hi(v.x);
        a0[2] += w * bf_lo(v.y); a0[3] += w * bf_hi(v.y);
        a0[4] += w * bf_lo(v.z); a0[5] += w * bf_hi(v.z);
        a0[6] += w * bf_lo(v.w); a0[7] += w * bf_hi(v.w);
    }
    float4 b0 = ((const float4*)bias)[c8 * 2];
    float4 b1v = ((const float4*)bias)[c8 * 2 + 1];
    float o[8];
    o[0] = dn * fmaxf(dn * (a0[0] + a1[0]) + b0.x, 0.f);
    o[1] = dn * fmaxf(dn * (a0[1] + a1[1]) + b0.y, 0.f);
    o[2] = dn * fmaxf(dn * (a0[2] + a1[2]) + b0.z, 0.f);
    o[3] = dn * fmaxf(dn * (a0[3] + a1[3]) + b0.w, 0.f);
    o[4] = dn * fmaxf(dn * (a0[4] + a1[4]) + b1v.x, 0.f);
    o[5] = dn * fmaxf(dn * (a0[5] + a1[5]) + b1v.y, 0.f);
    o[6] = dn * fmaxf(dn * (a0[6] + a1[6]) + b1v.z, 0.f);
    o[7] = dn * fmaxf(dn * (a0[7] + a1[7]) + b1v.w, 0.f);
    uint4 p;
    p.x = (unsigned int)f2bf(o[0]) | ((unsigned int)f2bf(o[1]) << 16);
    p.y = (unsigned int)f2bf(o[2]) | ((unsigned int)f2bf(o[3]) << 16);
    p.z = (unsigned int)f2bf(o[4]) | ((unsigned int)f2bf(o[5]) << 16);
    p.w = (unsigned int)f2bf(o[6]) | ((unsigned int)f2bf(o[7]) << 16);
    ((uint4*)outp)[(size_t)n * 8 + c8] = p;
}

// ---------------- Fused gather2 + GEMM2: 32-row tiles, 8 lanes/node ----------------
// Phase A: 8 lanes/node x 8 ch gather h1' (bf16, prescaled) -> fp32 LDS tile.
// Phase B: 2x4-microtile VALU GEMM vs combined [64][64] weights.
__global__ __launch_bounds__(256) void k_gg2(const int* __restrict__ off,
                                             const int* __restrict__ csr,
                                             const float* __restrict__ dinv,
                                             const unsigned short* __restrict__ hb,
                                             const float* __restrict__ W2, const float* __restrict__ b2,
                                             const float* __restrict__ W3, const float* __restrict__ b3,
                                             float* __restrict__ out) {
    __shared__ float as_[32][72];     // +8 pad
    __shared__ float wc[64 * 64];
    __shared__ float bc[64];
    const int t = threadIdx.x;
    const int row0 = blockIdx.x * 32;  // NN = 3125*32 exactly, no tail

    // stage combined weights
    #pragma unroll
    for (int i = 0; i < 16; ++i) {
        int f = t + i * 256;
        int k = f >> 6, c = f & 63;
        wc[f] = (c < 32) ? W2[k * 32 + c] : W3[k * 32 + (c - 32)];
    }
    if (t < 64) bc[t] = (t < 32) ? b2[t] : b3[t - 32];

    // phase A: gather agg2 rows into LDS (fp32), 8 lanes/node, 1 load/edge/lane
    {
        const int nl = t >> 3;              // 0..31
        const int n = row0 + nl;
        const int c8 = t & 7;
        const uint4* h4 = (const uint4*)hb;
        float dn = dinv[n];
        float acc[8];
        uint4 v = h4[(size_t)n * 8 + c8];   // self (h1b prescaled)
        acc[0] = bf_lo(v.x); acc[1] = bf_hi(v.x);
        acc[2] = bf_lo(v.y); acc[3] = bf_hi(v.y);
        acc[4] = bf_lo(v.z); acc[5] = bf_hi(v.z);
        acc[6] = bf_lo(v.w); acc[7] = bf_hi(v.w);
        int b = off[n], e = off[n + 1];
        for (int i = b; i < e; ++i) {
            int s = csr[i];
            uint4 u = h4[(size_t)s * 8 + c8];
            acc[0] += bf_lo(u.x); acc[1] += bf_hi(u.x);
            acc[2] += bf_lo(u.y); acc[3] += bf_hi(u.y);
            acc[4] += bf_lo(u.z); acc[5] += bf_hi(u.z);
            acc[6] += bf_lo(u.w); acc[7] += bf_hi(u.w);
        }
        float* dp = &as_[nl][c8 * 8];
        #pragma unroll
        for (int j = 0; j < 8; ++j) dp[j] = dn * acc[j];
    }
    __syncthreads();

    // phase B: GEMM, 2x4 micro-tile per thread (32x64 output)
    const int tc = t & 15;              // col group: cols tc*4..+3
    const int tr = t >> 4;              // row group: rows tr*2, tr*2+1
    float acc[2][4];
    #pragma unroll
    for (int i = 0; i < 2; ++i)
        #pragma unroll
        for (int j = 0; j < 4; ++j) acc[i][j] = 0.f;

    #pragma unroll 4
    for (int k = 0; k < 64; ++k) {
        float4 wv = *(const float4*)&wc[k * 64 + tc * 4];
        #pragma unroll
        for (int i = 0; i < 2; ++i) {
            float xv = as_[tr * 2 + i][k];
            acc[i][0] += xv * wv.x; acc[i][1] += xv * wv.y;
            acc[i][2] += xv * wv.z; acc[i][3] += xv * wv.w;
        }
    }
    const int c0 = tc * 4;
    float4 bias = *(float4*)&bc[c0];
    #pragma unroll
    for (int i = 0; i < 2; ++i) {
        int r = tr * 2 + i;
        float4 o = make_float4(acc[i][0] + bias.x, acc[i][1] + bias.y,
                               acc[i][2] + bias.z, acc[i][3] + bias.w);
        size_t row = (size_t)(row0 + r);
        float* p = (tc < 8) ? (out + row * 32 + c0)
                            : (out + (size_t)NN * 32 + row * 32 + (c0 - 32));
        *(float4*)p = o;
    }
}

extern "C" void kernel_launch(void* const* d_in, const int* in_sizes, int n_in,
                              void* d_out, int out_size, void* d_ws, size_t ws_size,
                              hipStream_t stream) {
    const float* x  = (const float*)d_in[0];
    const int* edges = (const int*)d_in[1];
    const float* W1 = (const float*)d_in[2];
    const float* b1 = (const float*)d_in[3];
    const float* W2 = (const float*)d_in[4];
    const float* b2 = (const float*)d_in[5];
    const float* W3 = (const float*)d_in[6];
    const float* b3 = (const float*)d_in[7];
    float* out = (float*)d_out;

    const int* srcs = edges;            // edges[0]
    const int* dsts = edges + NE;       // edges[1]

    // ws layout (4-byte words), total 8,205,280 words = 32.8 MB
    int*   csr_off = (int*)d_ws;                    // [NN+1]
    float* dinv    = (float*)((int*)d_ws + 100004); // [NN]
    int*   csr_src = (int*)d_ws + 200004;           // [NE]
    int*   bhist   = (int*)d_ws + 1800004;          // [NB]
    int*   boff    = (int*)d_ws + 1800396;          // [NB+1]
    int*   bcur    = (int*)d_ws + 1800788;          // [NB]
    unsigned short* wtb = (unsigned short*)((int*)d_ws + 1801184); // [64*128] bf16
    // region A: t1b [NN*64] bf16 — exclusive (written concurrently with pairs!)
    unsigned short* t1b = (unsigned short*)((int*)d_ws + 1805280); // 3.2e6 words
    // region B: pairs [NE uint] then h1b [NN*64] bf16 (pairs dead after k_fine)
    unsigned int*   pairs = (unsigned int*)((int*)d_ws + 5005280);
    unsigned short* h1b   = (unsigned short*)pairs;

    dim3 blk(256);
    const int gN8 = (NN * 8 + 255) / 256;   // 3125
    const int gT2 = NN / 32;                // 3125 (exact)

    // prologue: W1 transpose + zero bhist; histogram; bucket scan
    k_pre<<<32, blk, 0, stream>>>(W1, wtb, bhist);
    k_hist<<<256, blk, 0, stream>>>(dsts, bhist);
    k_scanb<<<1, blk, 0, stream>>>(bhist, boff, bcur);

    // fused: GEMM1 (782 tiles) ∥ bscatter (391 chunks), interleaved 2:1
    k_fuse<<<3 * NCHUNK, dim3(512), 0, stream>>>(x, wtb, t1b, srcs, dsts, bcur, pairs);

    k_fine<<<NB, blk, 0, stream>>>(pairs, boff, csr_off, csr_src, dinv);

    // conv1 aggregation: h1b = bf16(dinv*relu(dinv*Agg(t1)+b1))
    k_gather8<<<gN8, blk, 0, stream>>>(csr_off, csr_src, dinv, t1b, b1,
                                       (unsigned int*)h1b);
    // conv2/3: fused Agg(h1) + both GEMMs (32-row tiles, 8 lanes/node)
    k_gg2<<<gT2, blk, 0, stream>>>(csr_off, csr_src, dinv, h1b, W2, b2, W3, b3, out);
}

// Round 15
// 149.788 us; speedup vs baseline: 1.5052x; 1.0897x over previous
//
// GCNEncoder MI355X kernel — v11: gg2 un-fused via Agg(h'W)=Agg(h')W identity:
// MFMA k_gemm23 (y=h1'@[W2|W3]) + thin barrier-free k_gatherO (proven gather8
// structure, MLP=2, no LDS). v10's gg2 reverted (MLP-1 regression confirmed).
#include <hip/hip_runtime.h>

#define NN 100000
#define NE 1600000
#define NB 391            // ceil(NN/256) buckets of 256 nodes (bucket = dst >> 8)
#define CHUNK 4096
#define NCHUNK 391        // ceil(NE/CHUNK)

typedef __attribute__((ext_vector_type(8))) short short8_t;
typedef __attribute__((ext_vector_type(4))) float float4_t;

// ---- bf16 helpers (RNE pack, bit-op unpack) ----
__device__ inline unsigned short f2bf(float f) {
    unsigned int u = __float_as_uint(f);
    unsigned int r = u + 0x7fffu + ((u >> 16) & 1u);
    return (unsigned short)(r >> 16);
}
__device__ inline float bf_lo(unsigned int u) { return __uint_as_float(u << 16); }
__device__ inline float bf_hi(unsigned int u) { return __uint_as_float(u & 0xffff0000u); }

// ---------------- prologue: W1^T, [W2|W3]^T, zero bhist ----------------
__global__ __launch_bounds__(256) void k_pre(const float* __restrict__ W1,
                                             const float* __restrict__ W2,
                                             const float* __restrict__ W3,
                                             unsigned short* __restrict__ wtb,
                                             unsigned short* __restrict__ wt2,
                                             int* __restrict__ bhist) {
    int f = blockIdx.x * 256 + threadIdx.x;      // 0..8191
    int c = f >> 7, k = f & 127;
    wtb[f] = f2bf(W1[k * 64 + c]);               // wtb[c][k] = W1[k][c]
    if (f < 4096) {                              // wt2[c][k] = Wc[k][c], Wc=[W2|W3]
        int c2 = f >> 6, k2 = f & 63;
        float v = (c2 < 32) ? W2[k2 * 32 + c2] : W3[k2 * 32 + (c2 - 32)];
        wt2[f] = f2bf(v);
    }
    if (f < NB) bhist[f] = 0;
}

// ---------------- Pass A: coarse histogram (LDS-privatized) ----------------
__global__ __launch_bounds__(256) void k_hist(const int* __restrict__ dst,
                                              int* __restrict__ bhist) {
    __shared__ int lh[NB];
    int t = threadIdx.x;
    for (int i = t; i < NB; i += 256) lh[i] = 0;
    __syncthreads();
    for (int e = blockIdx.x * 256 + t; e < NE; e += 256 * 256)
        atomicAdd(&lh[dst[e] >> 8], 1);
    __syncthreads();
    for (int i = t; i < NB; i += 256)
        if (lh[i]) atomicAdd(&bhist[i], lh[i]);
}

// ---------------- Pass B: scan buckets -> boff, bcursor ----------------
__global__ __launch_bounds__(256) void k_scanb(const int* __restrict__ bhist,
                                               int* __restrict__ boff,
                                               int* __restrict__ bcur) {
    __shared__ int sh[256];
    int t = threadIdx.x;
    int base = t * 2;
    int v0 = (base + 0 < NB) ? bhist[base + 0] : 0;
    int v1 = (base + 1 < NB) ? bhist[base + 1] : 0;
    int tsum = v0 + v1;
    sh[t] = tsum;
    __syncthreads();
    for (int d = 1; d < 256; d <<= 1) {
        int x = (t >= d) ? sh[t - d] : 0;
        __syncthreads();
        sh[t] += x;
        __syncthreads();
    }
    int excl = sh[t] - tsum;
    if (base + 0 < NB) { boff[base + 0] = excl;      bcur[base + 0] = excl; }
    if (base + 1 < NB) { boff[base + 1] = excl + v0; bcur[base + 1] = excl + v0; }
    if (t == 255) boff[NB] = sh[255];   // == NE
}

// ---------------- FUSED: GEMM1 (MFMA, unscaled) ∥ bscatter ----------------
__global__ __launch_bounds__(512) void k_fuse(const float* __restrict__ x,
                                              const unsigned short* __restrict__ wtb,
                                              unsigned short* __restrict__ t1b,
                                              const int* __restrict__ src,
                                              const int* __restrict__ dst,
                                              int* __restrict__ bcur,
                                              unsigned int* __restrict__ pairs) {
    __shared__ __align__(16) unsigned char smem[52224];
    const int b = blockIdx.x;
    const int t = threadIdx.x;

    if ((b % 3) == 2) {
        // ---- bscatter role ----
        int* lh    = (int*)smem;          // [NB]
        int* lbase = lh + NB;             // [NB]
        int e0 = (b / 3) * CHUNK;
        int e1 = min(e0 + CHUNK, NE);
        for (int i = t; i < NB; i += 512) lh[i] = 0;
        __syncthreads();
        for (int e = e0 + t; e < e1; e += 512)
            atomicAdd(&lh[dst[e] >> 8], 1);
        __syncthreads();
        int rot = (int)(((unsigned)(b / 3) * 97u) % NB);   // stagger atomic bursts
        for (int i = t; i < NB; i += 512) {
            int ii = i + rot; if (ii >= NB) ii -= NB;
            int h = lh[ii];
            lbase[ii] = h ? atomicAdd(&bcur[ii], h) : 0;
        }
        __syncthreads();
        for (int i = t; i < NB; i += 512) lh[i] = 0;   // reuse as cursor
        __syncthreads();
        for (int e = e0 + t; e < e1; e += 512) {
            int d = dst[e];
            int bk = d >> 8;
            int r = atomicAdd(&lh[bk], 1);
            pairs[lbase[bk] + r] = (unsigned int)src[e] | ((unsigned int)(d & 255) << 17);
        }
    } else {
        // ---- gemm1 role ----
        unsigned short* lx = (unsigned short*)smem;            // [128*136]
        unsigned short* lw = (unsigned short*)(smem + 34816);  // [64*136]
        const int tile = 2 * (b / 3) + (b % 3);
        const int row0 = tile * 128;
        const int nrows = min(128, NN - row0);

        #pragma unroll
        for (int i = 0; i < 8; ++i) {
            int f = t + i * 512;            // 0..4095
            int r = f >> 5, c4 = f & 31;
            float4 v = make_float4(0.f, 0.f, 0.f, 0.f);
            if (r < nrows) v = ((const float4*)(x + (size_t)(row0 + r) * 128))[c4];
            ushort4 o;
            o.x = f2bf(v.x); o.y = f2bf(v.y); o.z = f2bf(v.z); o.w = f2bf(v.w);
            *(ushort4*)&lx[r * 136 + c4 * 4] = o;
        }
        #pragma unroll
        for (int i = 0; i < 2; ++i) {
            int f = t + i * 512;            // 0..1023 ; f = c*16 + c8
            int c = f >> 4, c8 = f & 15;
            uint4 v = ((const uint4*)wtb)[f];
            *(uint4*)&lw[c * 136 + c8 * 8] = v;
        }
        __syncthreads();

        const int w = t >> 6, l = t & 63;
        const int m15 = l & 15, kg = l >> 4;
        const unsigned short* pa = &lx[(w * 16 + m15) * 136 + kg * 8];
        const unsigned short* pb = &lw[m15 * 136 + kg * 8];

        float4_t acc[4];
        #pragma unroll
        for (int cb = 0; cb < 4; ++cb) acc[cb] = (float4_t){0.f, 0.f, 0.f, 0.f};

        #pragma unroll
        for (int ks = 0; ks < 4; ++ks) {
            short8_t a = *(const short8_t*)(pa + ks * 32);
            #pragma unroll
            for (int cb = 0; cb < 4; ++cb) {
                short8_t bb = *(const short8_t*)(pb + cb * (16 * 136) + ks * 32);
                acc[cb] = __builtin_amdgcn_mfma_f32_16x16x32_bf16(a, bb, acc[cb], 0, 0, 0);
            }
        }

        #pragma unroll
        for (int r = 0; r < 4; ++r) {
            int lrow = w * 16 + kg * 4 + r;
            if (lrow < nrows) {
                size_t grow = (size_t)(row0 + lrow);
                #pragma unroll
                for (int cb = 0; cb < 4; ++cb)
                    t1b[grow * 64 + cb * 16 + m15] = f2bf(acc[cb][r]);
            }
        }
    }
}

// ---------------- Pass D: per-bucket fine sort + dinv + csr_off ----------------
__global__ __launch_bounds__(256) void k_fine(const unsigned int* __restrict__ pairs,
                                              const int* __restrict__ boff,
                                              int* __restrict__ csr_off,
                                              int* __restrict__ csr_src,
                                              float* __restrict__ dinv) {
    __shared__ int lcnt[256];
    __shared__ int sc[256];
    __shared__ int lofs[256];
    int t = threadIdx.x;
    int b = blockIdx.x;
    int n0 = b << 8;
    int nnode = min(256, NN - n0);
    int bO = boff[b], bE = boff[b + 1];

    lcnt[t] = 0;
    __syncthreads();
    for (int e = bO + t; e < bE; e += 256)
        atomicAdd(&lcnt[pairs[e] >> 17], 1);
    __syncthreads();
    sc[t] = lcnt[t];
    __syncthreads();
    for (int d = 1; d < 256; d <<= 1) {
        int x = (t >= d) ? sc[t - d] : 0;
        __syncthreads();
        sc[t] += x;
        __syncthreads();
    }
    {
        int excl = sc[t] - lcnt[t];
        lofs[t] = excl;
        if (t < nnode) {
            int n = n0 + t;
            csr_off[n] = bO + excl;
            dinv[n] = rsqrtf(1.0f + (float)lcnt[t]);
        }
        lcnt[t] = 0;   // reuse as cursor
    }
    if (b == NB - 1 && t == 0) csr_off[NN] = NE;
    __syncthreads();
    for (int e = bO + t; e < bE; e += 256) {
        unsigned int w = pairs[e];
        int li = (int)(w >> 17);
        int r = atomicAdd(&lcnt[li], 1);
        csr_src[bO + lofs[li] + r] = (int)(w & 0x1FFFFu);
    }
}

// ---------------- gather1: h1b = bf16( dinv[n]*relu( dinv[n]*acc + b1 ) ) ----------------
// acc = dinv[n]*t1[n] + sum_e dinv[s]*t1[s]   (t1b unscaled; 8 lanes/node, 8 ch/lane)
__global__ __launch_bounds__(256) void k_gather8(const int* __restrict__ off,
                                                 const int* __restrict__ csr,
                                                 const float* __restrict__ dinv,
                                                 const unsigned short* __restrict__ hb,
                                                 const float* __restrict__ bias,
                                                 unsigned int* __restrict__ outp) {
    int idx = blockIdx.x * 256 + threadIdx.x;   // 8 lanes per node
    int n = idx >> 3;
    if (n >= NN) return;
    int c8 = idx & 7;                           // channels c8*8 .. c8*8+7
    const uint4* h4 = (const uint4*)hb;         // row stride = 8 uint4 (64 bf16)
    float dn = dinv[n];
    float a0[8], a1[8];
    {
        uint4 v = h4[(size_t)n * 8 + c8];       // self term: dn * t1[n]
        a0[0] = dn * bf_lo(v.x); a0[1] = dn * bf_hi(v.x);
        a0[2] = dn * bf_lo(v.y); a0[3] = dn * bf_hi(v.y);
        a0[4] = dn * bf_lo(v.z); a0[5] = dn * bf_hi(v.z);
        a0[6] = dn * bf_lo(v.w); a0[7] = dn * bf_hi(v.w);
        #pragma unroll
        for (int j = 0; j < 8; ++j) a1[j] = 0.f;
    }
    int b = off[n], e = off[n + 1];
    int i = b;
    for (; i + 1 < e; i += 2) {                 // 2-edge unroll, dual accumulators
        int s0 = csr[i], s1 = csr[i + 1];
        float w0 = dinv[s0], w1 = dinv[s1];
        uint4 v0 = h4[(size_t)s0 * 8 + c8];
        uint4 v1 = h4[(size_t)s1 * 8 + c8];
        a0[0] += w0 * bf_lo(v0.x); a0[1] += w0 * bf_hi(v0.x);
        a0[2] += w0 * bf_lo(v0.y); a0[3] += w0 * bf_hi(v0.y);
        a0[4] += w0 * bf_lo(v0.z); a0[5] += w0 * bf_hi(v0.z);
        a0[6] += w0 * bf_lo(v0.w); a0[7] += w0 * bf_hi(v0.w);
        a1[0] += w1 * bf_lo(v1.x); a1[1] += w1 * bf_hi(v1.x);
        a1[2] += w1 * bf_lo(v1.y); a1[3] += w1 * bf_hi(v1.y);
        a1[4] += w1 * bf_lo(v1.z); a1[5] += w1 * bf_hi(v1.z);
        a1[6] += w1 * bf_lo(v1.w); a1[7] += w1 * bf_hi(v1.w);
    }
    if (i < e) {
        int s = csr[i];
        float w = dinv[s];
        uint4 v = h4[(size_t)s * 8 + c8];
        a0[0] += w * bf_lo(v.x); a0[1] += w * bf_hi(v.x);
        a0[2] += w * bf_lo(v.y); a0[3] += w * bf_hi(v.y);
        a0[4] += w * bf_lo(v.z); a0[5] += w * bf_hi(v.z);
        a0[6] += w * bf_lo(v.w); a0[7] += w * bf_hi(v.w);
    }
    float4 b0 = ((const float4*)bias)[c8 * 2];
    float4 b1v = ((const float4*)bias)[c8 * 2 + 1];
    float o[8];
    o[0] = dn * fmaxf(dn * (a0[0] + a1[0]) + b0.x, 0.f);
    o[1] = dn * fmaxf(dn * (a0[1] + a1[1]) + b0.y, 0.f);
    o[2] = dn * fmaxf(dn * (a0[2] + a1[2]) + b0.z, 0.f);
    o[3] = dn * fmaxf(dn * (a0[3] + a1[3]) + b0.w, 0.f);
    o[4] = dn * fmaxf(dn * (a0[4] + a1[4]) + b1v.x, 0.f);
    o[5] = dn * fmaxf(dn * (a0[5] + a1[5]) + b1v.y, 0.f);
    o[6] = dn * fmaxf(dn * (a0[6] + a1[6]) + b1v.z, 0.f);
    o[7] = dn * fmaxf(dn * (a0[7] + a1[7]) + b1v.w, 0.f);
    uint4 p;
    p.x = (unsigned int)f2bf(o[0]) | ((unsigned int)f2bf(o[1]) << 16);
    p.y = (unsigned int)f2bf(o[2]) | ((unsigned int)f2bf(o[3]) << 16);
    p.z = (unsigned int)f2bf(o[4]) | ((unsigned int)f2bf(o[5]) << 16);
    p.w = (unsigned int)f2bf(o[6]) | ((unsigned int)f2bf(o[7]) << 16);
    ((uint4*)outp)[(size_t)n * 8 + c8] = p;
}

// ---------------- GEMM23 (MFMA): y = h1' @ [W2|W3]   [NN,64]x[64,64] ----------------
// A = h1b tile [128 rows][64 k] bf16 (LDS stride 72), B = wt2 [64 col][64 k] bf16.
// Same fragment mapping as gemm1 (verified): A row=l&15, k=(l>>4)*8+j; B col=l&15;
// C/D col=l&15, row=(l>>4)*4+reg.
__global__ __launch_bounds__(512) void k_gemm23(const unsigned short* __restrict__ h1b,
                                                const unsigned short* __restrict__ wt2,
                                                unsigned short* __restrict__ y) {
    __shared__ __align__(16) unsigned short lx[128 * 72];
    __shared__ __align__(16) unsigned short lw[64 * 72];
    const int t = threadIdx.x;
    const int row0 = blockIdx.x * 128;
    const int nrows = min(128, NN - row0);

    // stage h1b tile: 128 rows x 8 uint4
    #pragma unroll
    for (int i = 0; i < 2; ++i) {
        int f = t + i * 512;            // 0..1023
        int r = f >> 3, c8 = f & 7;
        uint4 v = make_uint4(0u, 0u, 0u, 0u);
        if (r < nrows) v = ((const uint4*)h1b)[(size_t)(row0 + r) * 8 + c8];
        *(uint4*)&lx[r * 72 + c8 * 8] = v;
    }
    // stage wt2: 64 cols x 8 uint4
    if (t < 512) {
        int c = t >> 3, c8 = t & 7;
        uint4 v = ((const uint4*)wt2)[t];
        *(uint4*)&lw[c * 72 + c8 * 8] = v;
    }
    __syncthreads();

    const int w = t >> 6, l = t & 63;
    const int m15 = l & 15, kg = l >> 4;
    const unsigned short* pa = &lx[(w * 16 + m15) * 72 + kg * 8];
    const unsigned short* pb = &lw[m15 * 72 + kg * 8];

    float4_t acc[4];
    #pragma unroll
    for (int cb = 0; cb < 4; ++cb) acc[cb] = (float4_t){0.f, 0.f, 0.f, 0.f};

    #pragma unroll
    for (int ks = 0; ks < 2; ++ks) {
        short8_t a = *(const short8_t*)(pa + ks * 32);
        #pragma unroll
        for (int cb = 0; cb < 4; ++cb) {
            short8_t bb = *(const short8_t*)(pb + cb * (16 * 72) + ks * 32);
            acc[cb] = __builtin_amdgcn_mfma_f32_16x16x32_bf16(a, bb, acc[cb], 0, 0, 0);
        }
    }

    #pragma unroll
    for (int r = 0; r < 4; ++r) {
        int lrow = w * 16 + kg * 4 + r;
        if (lrow < nrows) {
            size_t grow = (size_t)(row0 + lrow);
            #pragma unroll
            for (int cb = 0; cb < 4; ++cb)
                y[grow * 64 + cb * 16 + m15] = f2bf(acc[cb][r]);
        }
    }
}

// ---------------- gatherO: out[n] = dinv[n]*(y[n] + sum_e y[s]) + bias ----------------
// y carries source prescale; thin, no LDS, no barrier; 8 lanes/node, 2-edge unroll.
// cols 0..31 -> out1 (+b2), cols 32..63 -> out2 (+b3).
__global__ __launch_bounds__(256) void k_gatherO(const int* __restrict__ off,
                                                 const int* __restrict__ csr,
                                                 const float* __restrict__ dinv,
                                                 const unsigned short* __restrict__ yb,
                                                 const float* __restrict__ b2,
                                                 const float* __restrict__ b3,
                                                 float* __restrict__ out) {
    int idx = blockIdx.x * 256 + threadIdx.x;   // NN*8 == 3125*256 exactly
    int n = idx >> 3;
    int c8 = idx & 7;
    const uint4* h4 = (const uint4*)yb;
    float a0[8], a1[8];
    {
        uint4 v = h4[(size_t)n * 8 + c8];       // self term
        a0[0] = bf_lo(v.x); a0[1] = bf_hi(v.x);
        a0[2] = bf_lo(v.y); a0[3] = bf_hi(v.y);
        a0[4] = bf_lo(v.z); a0[5] = bf_hi(v.z);
        a0[6] = bf_lo(v.w); a0[7] = bf_hi(v.w);
        #pragma unroll
        for (int j = 0; j < 8; ++j) a1[j] = 0.f;
    }
    int b = off[n], e = off[n + 1];
    int i = b;
    for (; i + 1 < e; i += 2) {                 // 2-edge unroll, dual accumulators
        int s0 = csr[i], s1 = csr[i + 1];
        uint4 v0 = h4[(size_t)s0 * 8 + c8];
        uint4 v1 = h4[(size_t)s1 * 8 + c8];
        a0[0] += bf_lo(v0.x); a0[1] += bf_hi(v0.x);
        a0[2] += bf_lo(v0.y); a0[3] += bf_hi(v0.y);
        a0[4] += bf_lo(v0.z); a0[5] += bf_hi(v0.z);
        a0[6] += bf_lo(v0.w); a0[7] += bf_hi(v0.w);
        a1[0] += bf_lo(v1.x); a1[1] += bf_hi(v1.x);
        a1[2] += bf_lo(v1.y); a1[3] += bf_hi(v1.y);
        a1[4] += bf_lo(v1.z); a1[5] += bf_hi(v1.z);
        a1[6] += bf_lo(v1.w); a1[7] += bf_hi(v1.w);
    }
    if (i < e) {
        uint4 v = h4[(size_t)csr[i] * 8 + c8];
        a0[0] += bf_lo(v.x); a0[1] += bf_hi(v.x);
        a0[2] += bf_lo(v.y); a0[3] += bf_hi(v.y);
        a0[4] += bf_lo(v.z); a0[5] += bf_hi(v.z);
        a0[6] += bf_lo(v.w); a0[7] += bf_hi(v.w);
    }
    float dn = dinv[n];
    const float* bp = (c8 < 4) ? (b2 + c8 * 8) : (b3 + (c8 - 4) * 8);
    float4 q0 = *(const float4*)bp;
    float4 q1 = *(const float4*)(bp + 4);
    float4 o0, o1;
    o0.x = dn * (a0[0] + a1[0]) + q0.x;
    o0.y = dn * (a0[1] + a1[1]) + q0.y;
    o0.z = dn * (a0[2] + a1[2]) + q0.z;
    o0.w = dn * (a0[3] + a1[3]) + q0.w;
    o1.x = dn * (a0[4] + a1[4]) + q1.x;
    o1.y = dn * (a0[5] + a1[5]) + q1.y;
    o1.z = dn * (a0[6] + a1[6]) + q1.z;
    o1.w = dn * (a0[7] + a1[7]) + q1.w;
    float* op = (c8 < 4) ? (out + (size_t)n * 32 + c8 * 8)
                         : (out + (size_t)NN * 32 + (size_t)n * 32 + (c8 - 4) * 8);
    *(float4*)op = o0;
    *(float4*)(op + 4) = o1;
}

extern "C" void kernel_launch(void* const* d_in, const int* in_sizes, int n_in,
                              void* d_out, int out_size, void* d_ws, size_t ws_size,
                              hipStream_t stream) {
    const float* x  = (const float*)d_in[0];
    const int* edges = (const int*)d_in[1];
    const float* W1 = (const float*)d_in[2];
    const float* b1 = (const float*)d_in[3];
    const float* W2 = (const float*)d_in[4];
    const float* b2 = (const float*)d_in[5];
    const float* W3 = (const float*)d_in[6];
    const float* b3 = (const float*)d_in[7];
    float* out = (float*)d_out;

    const int* srcs = edges;            // edges[0]
    const int* dsts = edges + NE;       // edges[1]

    // ws layout (4-byte words), total 8,205,280 words = 32.8 MB (same as v8)
    int*   csr_off = (int*)d_ws;                    // [NN+1]
    float* dinv    = (float*)((int*)d_ws + 100004); // [NN]
    int*   csr_src = (int*)d_ws + 200004;           // [NE]
    int*   bhist   = (int*)d_ws + 1800004;          // [NB]
    int*   boff    = (int*)d_ws + 1800396;          // [NB+1]
    int*   bcur    = (int*)d_ws + 1800788;          // [NB]
    unsigned short* wtb = (unsigned short*)((int*)d_ws + 1801184); // [64*128] bf16
    // region A: t1b [NN*64] bf16 (exclusive during k_fuse); reused as y after gather8
    unsigned short* t1b = (unsigned short*)((int*)d_ws + 1805280);
    unsigned short* y   = t1b;          // t1b dead after k_gather8
    // region B: pairs [NE uint] then h1b [NN*64] bf16 (pairs dead after k_fine)
    unsigned int*   pairs = (unsigned int*)((int*)d_ws + 5005280);
    unsigned short* h1b   = (unsigned short*)pairs;
    // wt2 [64*64] bf16 (8 KB) staged in d_out tail: read by k_gemm23, then
    // fully overwritten by k_gatherO (stream-ordered) — zero ws growth.
    unsigned short* wt2 = (unsigned short*)(out + 6400000 - 2048);

    dim3 blk(256);
    const int gN8 = (NN * 8 + 255) / 256;   // 3125 (exact)
    const int gT23 = (NN + 127) / 128;      // 782

    // prologue: W transposes + zero bhist; histogram; bucket scan
    k_pre<<<32, blk, 0, stream>>>(W1, W2, W3, wtb, wt2, bhist);
    k_hist<<<256, blk, 0, stream>>>(dsts, bhist);
    k_scanb<<<1, blk, 0, stream>>>(bhist, boff, bcur);

    // fused: GEMM1 (782 tiles) ∥ bscatter (391 chunks), interleaved 2:1
    k_fuse<<<3 * NCHUNK, dim3(512), 0, stream>>>(x, wtb, t1b, srcs, dsts, bcur, pairs);

    k_fine<<<NB, blk, 0, stream>>>(pairs, boff, csr_off, csr_src, dinv);

    // conv1 aggregation: h1b = bf16(dinv*relu(dinv*Agg(t1)+b1))
    k_gather8<<<gN8, blk, 0, stream>>>(csr_off, csr_src, dinv, t1b, b1,
                                       (unsigned int*)h1b);
    // conv2/3: y = h1' @ [W2|W3] (MFMA), then thin gather to d_out
    k_gemm23<<<gT23, dim3(512), 0, stream>>>(h1b, wt2, y);
    k_gatherO<<<gN8, blk, 0, stream>>>(csr_off, csr_src, dinv, y, b2, b3, out);
}